// Round 4
// baseline (77.767 us; speedup 1.0000x reference)
//
#include <hip/hip_runtime.h>
#include <math.h>

// Problem constants (match reference)
#define BB 8192
#define NN 128
// SIGMA1 = 0.01, ALPHA = BETA = 0.5

typedef float vf4 __attribute__((ext_vector_type(4)));

constexpr int BLOCK = 256;
constexpr int EPT = 4;                              // elements per thread
constexpr int GRID = (BB * NN) / (BLOCK * EPT);     // 1024 blocks

// Fused: per-block partial sums; last-arriving block reduces all partials.
//   s1 = sum log(niw_var)          (= psi_d - log(denom))
//   s2 = sum 1/niw_var             (SIGMA1 applied at the end)
//   s3 = sum d^2 / niw_var
//   s4 = sum |d| * (lmbda + nu)
__global__ __launch_bounds__(BLOCK) void niw_fused_kernel(
    const float* __restrict__ y, const float* __restrict__ mu,
    const float* __restrict__ lmbda, const float* __restrict__ psi,
    const float* __restrict__ nu, double* __restrict__ partials,
    unsigned* __restrict__ counter, float* __restrict__ out)
{
    const int t = blockIdx.x * BLOCK + threadIdx.x;
    const int e = t * EPT;               // first element index (multiple of 4)
    const int b = e >> 7;                // row (N=128)
    const int j = e & 127;               // col within row (multiple of 4)

    // --- scattered psi diagonal loads first: longest latency, no reuse -> nt
    const float* prow = psi + (size_t)b * (NN * NN) + (size_t)j * (NN + 1);
    const float pd[4] = {
        __builtin_nontemporal_load(prow),
        __builtin_nontemporal_load(prow + 129),
        __builtin_nontemporal_load(prow + 258),
        __builtin_nontemporal_load(prow + 387)};

    // --- contiguous streams, float4 per thread
    const vf4 yv  = __builtin_nontemporal_load(reinterpret_cast<const vf4*>(y + e));
    const vf4 muv = __builtin_nontemporal_load(reinterpret_cast<const vf4*>(mu + e));
    const vf4 lmv = __builtin_nontemporal_load(reinterpret_cast<const vf4*>(lmbda + e));
    const vf4 nuv = __builtin_nontemporal_load(reinterpret_cast<const vf4*>(nu + e));

    float s1 = 0.f, s2 = 0.f, s3 = 0.f, s4 = 0.f;
#pragma unroll
    for (int k = 0; k < 4; ++k) {
        float yk = yv[k];
        yk = (yk != yk) ? 0.0f : yk;     // nan_to_num
        const float d = muv[k] - yk;
        const float denom = lmv[k] * (nuv[k] - (float)(NN + 1));  // lmbda*(nu-n-1)
        s1 += pd[k] - __logf(denom);                              // log(niw_var)
        const float inv_v = denom * __expf(-pd[k]);               // 1/niw_var
        s2 += inv_v;
        s3 += d * d * inv_v;
        s4 += fabsf(d) * (lmv[k] + nuv[k]);
    }

    // wave (64-lane) reduction in float (abs threshold ~1.8e5; fp32 ample)
#pragma unroll
    for (int off = 32; off > 0; off >>= 1) {
        s1 += __shfl_down(s1, off);
        s2 += __shfl_down(s2, off);
        s3 += __shfl_down(s3, off);
        s4 += __shfl_down(s4, off);
    }

    __shared__ float sh[4][4];           // [wave][accum]
    __shared__ bool is_last;
    const int wave = threadIdx.x >> 6;
    const int lane = threadIdx.x & 63;
    if (lane == 0) {
        sh[wave][0] = s1; sh[wave][1] = s2; sh[wave][2] = s3; sh[wave][3] = s4;
    }
    __syncthreads();
    if (threadIdx.x == 0) {
        double t1 = 0, t2 = 0, t3 = 0, t4 = 0;
        for (int w = 0; w < 4; ++w) {
            t1 += sh[w][0]; t2 += sh[w][1]; t3 += sh[w][2]; t4 += sh[w][3];
        }
        double* p = partials + (size_t)blockIdx.x * 4;
        p[0] = t1; p[1] = t2; p[2] = t3; p[3] = t4;
        __threadfence();                               // release partials device-wide
        const unsigned prev = atomicAdd(counter, 1u);  // device-scope
        is_last = (prev == (unsigned)(GRID - 1));
    }
    __syncthreads();
    if (!is_last) return;

    // ---- last block: final reduction over all partials (deterministic order)
    __threadfence();                                   // acquire
    double t1 = 0, t2 = 0, t3 = 0, t4 = 0;
    for (int i = threadIdx.x; i < GRID; i += BLOCK) {
        const double* p = partials + (size_t)i * 4;
        t1 += p[0]; t2 += p[1]; t3 += p[2]; t4 += p[3];
    }
#pragma unroll
    for (int off = 32; off > 0; off >>= 1) {
        t1 += __shfl_down(t1, off);
        t2 += __shfl_down(t2, off);
        t3 += __shfl_down(t3, off);
        t4 += __shfl_down(t4, off);
    }
    __shared__ double shd[4][4];
    if (lane == 0) {
        shd[wave][0] = t1; shd[wave][1] = t2; shd[wave][2] = t3; shd[wave][3] = t4;
    }
    __syncthreads();
    if (threadIdx.x == 0) {
        double S1 = 0, S2 = 0, S3 = 0, S4 = 0;
        for (int w = 0; w < 4; ++w) {
            S1 += shd[w][0]; S2 += shd[w][1]; S3 += shd[w][2]; S4 += shd[w][3];
        }
        const double SIGMA1 = 0.01;
        const double n = (double)NN;
        const double Bd = (double)BB;
        // temporal = 0.5 * ( S1 - B*n*log(SIGMA1) - B*n + SIGMA1*S2 + S3 )
        const double temporal =
            0.5 * (S1 - Bd * n * log(SIGMA1) - Bd * n + SIGMA1 * S2 + S3);
        const double error = S4 / Bd;
        const double loss = 0.5 * temporal + 0.5 * error;
        out[0] = (float)loss;
        out[1] = (float)temporal;
        out[2] = (float)error;
    }
}

extern "C" void kernel_launch(void* const* d_in, const int* in_sizes, int n_in,
                              void* d_out, int out_size, void* d_ws, size_t ws_size,
                              hipStream_t stream) {
    const float* y     = (const float*)d_in[0];
    const float* mu    = (const float*)d_in[1];
    const float* lmbda = (const float*)d_in[2];
    const float* psi   = (const float*)d_in[3];
    const float* nu    = (const float*)d_in[4];
    float* out = (float*)d_out;

    // ws layout: [0,64) counter (+pad), [64, 64 + GRID*4*8) partials
    unsigned* counter = (unsigned*)d_ws;
    double* partials  = (double*)((char*)d_ws + 64);

    hipMemsetAsync(counter, 0, 64, stream);  // reset election counter each call
    niw_fused_kernel<<<GRID, BLOCK, 0, stream>>>(y, mu, lmbda, psi, nu,
                                                 partials, counter, out);
}

// Round 5
// 30.467 us; speedup vs baseline: 2.5525x; 2.5525x over previous
//
#include <hip/hip_runtime.h>
#include <math.h>

// Problem constants (match reference)
#define BB 8192
#define NN 128
// SIGMA1 = 0.01, ALPHA = BETA = 0.5

typedef float vf4 __attribute__((ext_vector_type(4)));

constexpr int BLOCK = 256;
constexpr int EPT = 4;                              // elements per thread
constexpr int GRID = (BB * NN) / (BLOCK * EPT);     // 1024 blocks

// Stage 1: per-block partial sums of
//   s1 = sum log(niw_var)          (= psi_d - log(denom))
//   s2 = sum 1/niw_var             (SIGMA1 applied at the end)
//   s3 = sum d^2 / niw_var
//   s4 = sum |d| * (lmbda + nu)
__global__ __launch_bounds__(BLOCK) void niw_reduce_kernel(
    const float* __restrict__ y, const float* __restrict__ mu,
    const float* __restrict__ lmbda, const float* __restrict__ psi,
    const float* __restrict__ nu, float* __restrict__ partials)
{
    const int t = blockIdx.x * BLOCK + threadIdx.x;
    const int e = t * EPT;               // first element index (multiple of 4)
    const int b = e >> 7;                // row (N=128)
    const int j = e & 127;               // col within row (multiple of 4)

    // scattered psi diagonal loads first (longest latency)
    const float* prow = psi + (size_t)b * (NN * NN) + (size_t)j * (NN + 1);
    const float pd[4] = {prow[0], prow[129], prow[258], prow[387]};

    // contiguous streams, float4 per thread
    const vf4 yv  = *reinterpret_cast<const vf4*>(y + e);
    const vf4 muv = *reinterpret_cast<const vf4*>(mu + e);
    const vf4 lmv = *reinterpret_cast<const vf4*>(lmbda + e);
    const vf4 nuv = *reinterpret_cast<const vf4*>(nu + e);

    float s1 = 0.f, s2 = 0.f, s3 = 0.f, s4 = 0.f;
#pragma unroll
    for (int k = 0; k < 4; ++k) {
        float yk = yv[k];
        yk = (yk != yk) ? 0.0f : yk;     // nan_to_num
        const float d = muv[k] - yk;
        const float denom = lmv[k] * (nuv[k] - (float)(NN + 1));  // lmbda*(nu-n-1)
        s1 += pd[k] - __logf(denom);                              // log(niw_var)
        const float inv_v = denom * __expf(-pd[k]);               // 1/niw_var
        s2 += inv_v;
        s3 += d * d * inv_v;
        s4 += fabsf(d) * (lmv[k] + nuv[k]);
    }

    // wave (64-lane) reduction in float (abs threshold ~1.8e5; fp32 ample)
#pragma unroll
    for (int off = 32; off > 0; off >>= 1) {
        s1 += __shfl_down(s1, off);
        s2 += __shfl_down(s2, off);
        s3 += __shfl_down(s3, off);
        s4 += __shfl_down(s4, off);
    }

    __shared__ float sh[4][4];           // [wave][accum]
    const int wave = threadIdx.x >> 6;
    const int lane = threadIdx.x & 63;
    if (lane == 0) {
        sh[wave][0] = s1; sh[wave][1] = s2; sh[wave][2] = s3; sh[wave][3] = s4;
    }
    __syncthreads();
    if (threadIdx.x == 0) {
        vf4 p;
        p[0] = sh[0][0] + sh[1][0] + sh[2][0] + sh[3][0];
        p[1] = sh[0][1] + sh[1][1] + sh[2][1] + sh[3][1];
        p[2] = sh[0][2] + sh[1][2] + sh[2][2] + sh[3][2];
        p[3] = sh[0][3] + sh[1][3] + sh[2][3] + sh[3][3];
        *reinterpret_cast<vf4*>(partials + (size_t)blockIdx.x * 4) = p;
    }
}

// Stage 2: single block sums the GRID partials, emits (loss, temporal, error)
__global__ __launch_bounds__(256) void niw_finalize_kernel(
    const float* __restrict__ partials, float* __restrict__ out)
{
    double t1 = 0, t2 = 0, t3 = 0, t4 = 0;
    for (int i = threadIdx.x; i < GRID; i += 256) {
        const vf4 p = *reinterpret_cast<const vf4*>(partials + (size_t)i * 4);
        t1 += p[0]; t2 += p[1]; t3 += p[2]; t4 += p[3];
    }
#pragma unroll
    for (int off = 32; off > 0; off >>= 1) {
        t1 += __shfl_down(t1, off);
        t2 += __shfl_down(t2, off);
        t3 += __shfl_down(t3, off);
        t4 += __shfl_down(t4, off);
    }
    __shared__ double sh[4][4];
    const int wave = threadIdx.x >> 6;
    const int lane = threadIdx.x & 63;
    if (lane == 0) {
        sh[wave][0] = t1; sh[wave][1] = t2; sh[wave][2] = t3; sh[wave][3] = t4;
    }
    __syncthreads();
    if (threadIdx.x == 0) {
        double S1 = 0, S2 = 0, S3 = 0, S4 = 0;
        for (int w = 0; w < 4; ++w) {
            S1 += sh[w][0]; S2 += sh[w][1]; S3 += sh[w][2]; S4 += sh[w][3];
        }
        const double SIGMA1 = 0.01;
        const double n = (double)NN;
        const double Bd = (double)BB;
        // temporal = 0.5 * ( S1 - B*n*log(SIGMA1) - B*n + SIGMA1*S2 + S3 )
        const double temporal =
            0.5 * (S1 - Bd * n * log(SIGMA1) - Bd * n + SIGMA1 * S2 + S3);
        const double error = S4 / Bd;
        const double loss = 0.5 * temporal + 0.5 * error;
        out[0] = (float)loss;
        out[1] = (float)temporal;
        out[2] = (float)error;
    }
}

extern "C" void kernel_launch(void* const* d_in, const int* in_sizes, int n_in,
                              void* d_out, int out_size, void* d_ws, size_t ws_size,
                              hipStream_t stream) {
    const float* y     = (const float*)d_in[0];
    const float* mu    = (const float*)d_in[1];
    const float* lmbda = (const float*)d_in[2];
    const float* psi   = (const float*)d_in[3];
    const float* nu    = (const float*)d_in[4];
    float* out = (float*)d_out;
    float* partials = (float*)d_ws;      // GRID*4*4 = 16 KiB

    niw_reduce_kernel<<<GRID, BLOCK, 0, stream>>>(y, mu, lmbda, psi, nu, partials);
    niw_finalize_kernel<<<1, 256, 0, stream>>>(partials, out);
}